// Round 1
// 210.595 us; speedup vs baseline: 1.0001x; 1.0001x over previous
//
#include <hip/hip_runtime.h>

// CRF NLL: B=1024, S=512, T=48.  ONE wave per batch element (1024x64).
// R5: fuse the fwd chain (lanes 0..23, outputs 2l,2l+1) and bwd chain
// (lanes 32..55) into the SAME wave instructions.  Each lane computes TWO
// outputs (2x24 dot2 vs the old 1x24 over 48 lanes -> identical dot count),
// but the 6 ds_read_b128 state broadcasts per step now serve BOTH chains
// (was 12), and reads are exec-masked to 48 lanes: LDS broadcast return
// traffic drops 12.3KB -> 4.6KB per jiter.  Theory: the old kernel was
// LDS-return-bandwidth bound (12 x 1KiB broadcast returns/jiter x 4
// waves/CU ~ 560cyc service; VALUBusy only 22%, conflicts 0).
// E' = exp(trans) * 2^-8 folded scale keeps f16-published values in range;
// exact pow2 probe-rescale every 4 iters; publish clamped at 60000.

#define T 48
#define SLEN 512
#define BATCH 1024

typedef _Float16 h2 __attribute__((ext_vector_type(2)));
typedef _Float16 h8v __attribute__((ext_vector_type(8)));
typedef h8v h8 __attribute__((may_alias));
typedef h2 h2ma __attribute__((may_alias));

__device__ __forceinline__ float wave_sum(float v) {
#pragma unroll
    for (int m = 32; m >= 1; m >>= 1) v += __shfl_xor(v, m, 64);
    return v;
}
__device__ __forceinline__ float wave_max(float v) {
#pragma unroll
    for (int m = 32; m >= 1; m >>= 1) v = fmaxf(v, __shfl_xor(v, m, 64));
    return v;
}
__device__ __forceinline__ float rlane(float v, int k) {
    return __int_as_float(__builtin_amdgcn_readlane(__float_as_int(v), k));
}
__device__ __forceinline__ float fdot2(h2 a, h2 b, float c) {
#if __has_builtin(__builtin_amdgcn_fdot2)
    return __builtin_amdgcn_fdot2(a, b, c, false);
#else
    return fmaf((float)a[1], (float)b[1], fmaf((float)a[0], (float)b[0], c));
#endif
}

#define H2OF(q, i) (__builtin_shufflevector((q), (q), 2*(i), 2*(i)+1))

// one q register (h8 = 4 k-pairs) against both outputs' fragments
#define DG(qr, t)                              \
    a0 = fdot2(H2OF(qr,0), EA[(t)+0], a0);     \
    c0 = fdot2(H2OF(qr,0), EB[(t)+0], c0);     \
    a1 = fdot2(H2OF(qr,1), EA[(t)+1], a1);     \
    c1 = fdot2(H2OF(qr,1), EB[(t)+1], c1);     \
    a2 = fdot2(H2OF(qr,2), EA[(t)+2], a2);     \
    c2 = fdot2(H2OF(qr,2), EB[(t)+2], c2);     \
    a3 = fdot2(H2OF(qr,3), EA[(t)+3], a3);     \
    c3 = fdot2(H2OF(qr,3), EB[(t)+3], c3);

#define DOT96() DG(q0,0) DG(q1,4) DG(q2,8) DG(q3,12) DG(q4,16) DG(q5,20)

__global__ __launch_bounds__(64) void crf_kernel(
    const float* __restrict__ em,      // (B,S,T)
    const int*   __restrict__ tags,    // (B,S)
    const float* __restrict__ mask,    // (B,S)
    const float* __restrict__ trans,   // (T,T)
    const float* __restrict__ start_t, // (T,)
    const float* __restrict__ end_t,   // (T,)
    float*       __restrict__ out)     // scalar
{
    constexpr float LOG2E = 1.4426950408889634f;
    constexpr float LN2   = 0.6931471805599453f;
    constexpr float ESC   = -8.0f;     // fold 2^-8 into E' for f16 range

    const int  b    = blockIdx.x;
    const int  lane = threadIdx.x;
    const bool isF  = lane < 32;       // lanes 0..31 fwd side, 32..63 bwd side
    const int  l31  = lane & 31;
    const bool act  = l31 < 24;        // 24 active lanes per chain (2 outputs each)
    const int  lc   = act ? l31 : 23;  // inactive lanes duplicate lane 23
    const int  j0   = 2 * lc, j1 = j0 + 1;

    const float* em_b   = em   + (size_t)b * SLEN * T;
    const float* mask_b = mask + (size_t)b * SLEN;
    const int*   tags_b = tags + (size_t)b * SLEN;

    // ---- sequence length ----
    float msum = 0.f;
    for (int s = lane; s < SLEN; s += 64) msum += mask_b[s];
    msum = wave_sum(msum);
    const int len = (int)(msum + 0.5f);
    const int nb  = (len - 1) >> 1;           // bwd steps (joint iters)
    const int nf  = (len - 1) - nb;           // fwd steps = nb or nb+1

    // ---- gold path score ----
    float g = 0.f;
    for (int i = lane; i < len; i += 64) {
        if (i >= 1) {
            const int tc = tags_b[i];
            const int tp = tags_b[i - 1];
            g += trans[tc * T + tp] + em_b[(size_t)i * T + tc];
        }
    }
    g = wave_sum(g);

    // ---- packed E' fragments: F-lanes hold columns j0,j1; B-lanes rows j0,j1
    h2 EA[24], EB[24];
#pragma unroll
    for (int k = 0; k < T; k += 2) {
        const int iA0 = isF ? ((k    ) * T + j0) : (j0 * T + k    );
        const int iA1 = isF ? ((k + 1) * T + j0) : (j0 * T + k + 1);
        const int iB0 = isF ? ((k    ) * T + j1) : (j1 * T + k    );
        const int iB1 = isF ? ((k + 1) * T + j1) : (j1 * T + k + 1);
        h2 ea, eb;
        ea[0] = (_Float16)exp2f(trans[iA0] * LOG2E + ESC);
        ea[1] = (_Float16)exp2f(trans[iA1] * LOG2E + ESC);
        eb[0] = (_Float16)exp2f(trans[iB0] * LOG2E + ESC);
        eb[1] = (_Float16)exp2f(trans[iB1] * LOG2E + ESC);
        EA[k >> 1] = ea; EB[k >> 1] = eb;
    }

    const float* ep2 = em_b + j0;
    const int maxoff = (SLEN - 1) * T;
    const float2 vlast2  = *(const float2*)(ep2 + (size_t)(len - 1) * T); // bwd init weights
    const float2 vextra2 = *(const float2*)(ep2 + (size_t)nf * T);        // extra fwd weights

    // ---- init state (st0,st1 = this lane's two state values) ----
    const float za = (start_t[j0] + em_b[j0]) * LOG2E;
    const float zb = (start_t[j1] + em_b[j1]) * LOG2E;
    const float m0 = wave_max(isF ? fmaxf(za, zb) : -1e30f);
    float st0, st1, L;
    if (isF) {
        st0 = exp2f(za - m0); st1 = exp2f(zb - m0); L = m0;
    } else {
        st0 = exp2f(end_t[j0] * LOG2E);
        st1 = exp2f(end_t[j1] * LOG2E);
        L = 0.f;
    }

    // state buffers: F at f16[0..47], pad, B at f16[64..111], pad.
    // write index 2*lane lands F-lanes in bufF, B-lanes in bufB, idles in pads.
    __shared__ __align__(16) _Float16 sh[128];
    {
        const float w0 = exp2f(vlast2.x * LOG2E);
        const float w1 = exp2f(vlast2.y * LOG2E);
        h2 p;
        p[0] = (_Float16)(isF ? st0 : fminf(st0 * w0, 60000.f));
        p[1] = (_Float16)(isF ? st1 : fminf(st1 * w1, 60000.f));
        *(h2ma*)&sh[2 * lane] = p;
    }
    const h8* Qb = (const h8*)(sh + ((lane & 32) << 1)); // F: byte 0, B: byte 128
    h8 q0 = {}, q1 = {}, q2 = {}, q3 = {}, q4 = {}, q5 = {};
    if (act) { q0 = Qb[0]; q1 = Qb[1]; q2 = Qb[2]; q3 = Qb[3]; q4 = Qb[4]; q5 = Qb[5]; }

    // ---- emission ring (float2 per lane: raw em for its two outputs) ----
    const int dlt = isF ? T : -T;
    int off = isF ? T : (len - 2) * T;
    auto ldem = [&]() -> float2 {
        int oc = off;
        oc = oc < 0 ? 0 : oc;
        oc = oc > maxoff ? maxoff : oc;
        const float2 r = *(const float2*)(ep2 + oc);
        off += dlt;
        return r;
    };
    float2 r0 = ldem(), r1 = ldem(), r2 = ldem(), r3 = ldem();

    auto jiter = [&](float2& slot, bool resc) {
        const float w0 = exp2f(slot.x * LOG2E);
        const float w1 = exp2f(slot.y * LOG2E);
        slot = ldem();
        float a0=0.f,a1=0.f,a2=0.f,a3=0.f,c0=0.f,c1=0.f,c2=0.f,c3=0.f;
        DOT96()
        float s0 = (a0 + a1) + (a2 + a3);
        float s1 = (c0 + c1) + (c2 + c3);
        if (isF) { s0 *= w0; s1 *= w1; }   // fwd: dest weight at compute
        if (resc) {                        // exact pow2, probe both groups
            const float m  = fmaxf(s0, s1);
            const float mf = fmaxf(fmaxf(rlane(m, 0),  rlane(m, 8)),
                                   fmaxf(rlane(m, 16), rlane(m, 23)));
            const float mb = fmaxf(fmaxf(rlane(m, 32), rlane(m, 40)),
                                   fmaxf(rlane(m, 48), rlane(m, 55)));
            int e = ((__float_as_int(isF ? mf : mb) >> 23) & 255) - 127;
            e = e < -64 ? -64 : e;
            const float sc = __int_as_float((127 - e) << 23);
            s0 *= sc; s1 *= sc; L += (float)e;
        }
        st0 = s0; st1 = s1;
        h2 p;                              // bwd: weight applied at publish
        p[0] = (_Float16)fminf(isF ? s0 : s0 * w0, 60000.f);
        p[1] = (_Float16)fminf(isF ? s1 : s1 * w1, 60000.f);
        *(h2ma*)&sh[2 * lane] = p;
        if (act) { q0 = Qb[0]; q1 = Qb[1]; q2 = Qb[2]; q3 = Qb[3]; q4 = Qb[4]; q5 = Qb[5]; }
    };

    int rem = nb;
    while (rem >= 4) {
        jiter(r0, false); jiter(r1, false); jiter(r2, false); jiter(r3, true);
        rem -= 4;
    }
    if (rem > 0) { jiter(r0, false);
        if (rem > 1) { jiter(r1, false);
            if (rem > 2) jiter(r2, false); } }

    // ---- finalize: undo folded 2^-8 per step ----
    L += 8.0f * (float)(isF ? nf : nb);

    // extra forward step (nf = nb+1 case); q holds p_nb broadcast in F-lanes
    if (nf > nb) {
        const float w0 = exp2f(vextra2.x * LOG2E);
        const float w1 = exp2f(vextra2.y * LOG2E);
        float a0=0.f,a1=0.f,a2=0.f,a3=0.f,c0=0.f,c1=0.f,c2=0.f,c3=0.f;
        DOT96()
        if (isF) {
            st0 = ((a0 + a1) + (a2 + a3)) * w0;
            st1 = ((c0 + c1) + (c2 + c3)) * w1;
        }
    }

    // ---- combine at m = nf: Z = sum_j p[j]*u[j]; u lives 32 lanes up ----
    const float u0 = __shfl_xor(st0, 32, 64);
    const float u1 = __shfl_xor(st1, 32, 64);
    const float v  = (isF && act) ? (st0 * u0 + st1 * u1) : 0.f;
    const float S_ = wave_sum(v);
    const float Lf = rlane(L, 0);
    const float Lb = rlane(L, 32);
    const float fwd = (Lf + Lb + log2f(S_)) * LN2;

    if (lane == 0) {
        const int t0 = tags_b[0];
        const int tl = tags_b[len - 1];
        const float gold = g + start_t[t0] + em_b[t0] + end_t[tl];
        atomicAdd(out, (fwd - gold) * (1.0f / (float)BATCH));
    }
}

extern "C" void kernel_launch(void* const* d_in, const int* in_sizes, int n_in,
                              void* d_out, int out_size, void* d_ws, size_t ws_size,
                              hipStream_t stream) {
    const float* em      = (const float*)d_in[0];
    const int*   tags    = (const int*)  d_in[1];
    const float* mask    = (const float*)d_in[2];
    const float* trans   = (const float*)d_in[3];
    const float* start_t = (const float*)d_in[4];
    const float* end_t   = (const float*)d_in[5];
    float* out = (float*)d_out;

    hipMemsetAsync(out, 0, sizeof(float), stream);
    crf_kernel<<<BATCH, 64, 0, stream>>>(em, tags, mask, trans, start_t, end_t, out);
}